// Round 4
// baseline (46.605 us; speedup 1.0000x reference)
//
#include <hip/hip_runtime.h>

#define Bq 32
#define Jq 16
#define Hq 256
#define Wq 256
#define Cn 7
#define HW (Hq * Wq)          // 65536 per (b,j)
#define NBJ (Bq * Jq)         // 512 blocks, one per (b,j)
#define TPB 256

// ws layout: [0..511] float candidate vals | [512..1023] int candidate idx |
//            [1024]   int arrival counter (memset to 0 each call)
#define WS_VAL 0
#define WS_IDX (NBJ * sizeof(float))
#define WS_CNT (2 * NBJ * sizeof(float))

__global__ __launch_bounds__(TPB) void labelloss_fused_kernel(
    const float* __restrict__ pred,
    const float* __restrict__ gt,
    const float* __restrict__ heatmap,
    float* __restrict__ wsv,
    int*   __restrict__ wsi,
    int*   __restrict__ counter,
    float* __restrict__ out)
{
    const int bj  = blockIdx.x;        // 0..511
    const int tid = threadIdx.x;

    // ---- Phase 1: per-(b,j) argmax over 65536 floats (R0's best loop) ----
    const float4* hm = (const float4*)(heatmap + (size_t)bj * HW);

    float best = -3.402823466e+38f;
    int   bidx = 0x7fffffff;

    #pragma unroll 4
    for (int it = 0; it < HW / 4 / TPB; ++it) {
        const int v4   = it * TPB + tid;
        const float4 v = hm[v4];
        const int base = v4 * 4;
        // Strict '>' keeps earliest index (thread scans increasing idx).
        if (v.x > best) { best = v.x; bidx = base;     }
        if (v.y > best) { best = v.y; bidx = base + 1; }
        if (v.z > best) { best = v.z; bidx = base + 2; }
        if (v.w > best) { best = v.w; bidx = base + 3; }
    }

    #pragma unroll
    for (int off = 32; off > 0; off >>= 1) {
        const float ov = __shfl_down(best, off);
        const int   oi = __shfl_down(bidx, off);
        if (ov > best || (ov == best && oi < bidx)) { best = ov; bidx = oi; }
    }

    __shared__ float sval[TPB / 64];
    __shared__ int   sidx[TPB / 64];
    __shared__ int   s_old;
    const int wave = tid >> 6;
    const int lane = tid & 63;
    if (lane == 0) { sval[wave] = best; sidx[wave] = bidx; }
    __syncthreads();

    if (tid == 0) {
        #pragma unroll
        for (int w = 1; w < TPB / 64; ++w) {
            if (sval[w] > best || (sval[w] == best && sidx[w] < bidx)) {
                best = sval[w]; bidx = sidx[w];
            }
        }
        wsv[bj] = best;
        wsi[bj] = bidx;
        __threadfence();                       // publish before arrival
        s_old = atomicAdd(counter, 1);         // device-scope by default
    }
    __syncthreads();

    // ---- Phase 2: the LAST block to arrive computes the final output ----
    if (s_old == NBJ - 1) {
        __threadfence();                       // acquire all candidates
        __shared__ float sloss[NBJ];

        #pragma unroll
        for (int r = 0; r < NBJ / TPB; ++r) {  // each thread: 2 bj entries
            const int mbj = r * TPB + tid;
            const int mb  = mbj >> 4;
            const float pv_best = wsv[mbj];
            float loss = 0.0f;
            if (pv_best == 1.0f) {
                const int fi = wsi[mbj];
                const int x  = fi >> 8;        // idx / 256
                const int y  = fi & 255;       // idx % 256
                const float* gp = gt + (size_t)mbj * Cn;
                #pragma unroll
                for (int c = 0; c < Cn; ++c) {
                    const float pv = pred[(((size_t)mb * Cn + c) * Hq + x) * Wq + y];
                    const float d  = pv - gp[c];
                    loss += d * d;
                }
            }
            sloss[mbj] = loss;
        }
        __syncthreads();

        if (tid < Bq) {
            float s = 0.0f;
            #pragma unroll
            for (int j = 0; j < Jq; ++j) s += sloss[tid * Jq + j];
            out[tid] = s;                      // all 32 outputs, every call
        }
    }
}

extern "C" void kernel_launch(void* const* d_in, const int* in_sizes, int n_in,
                              void* d_out, int out_size, void* d_ws, size_t ws_size,
                              hipStream_t stream)
{
    const float* pred    = (const float*)d_in[0];   // (B, C, H, W) f32
    const float* gt      = (const float*)d_in[1];   // (B, J, C)   f32
    const float* heatmap = (const float*)d_in[2];   // (B, J, H, W) f32
    float* out = (float*)d_out;                     // (B,) f32

    float* wsv     = (float*)((char*)d_ws + WS_VAL);
    int*   wsi     = (int*)  ((char*)d_ws + WS_IDX);
    int*   counter = (int*)  ((char*)d_ws + WS_CNT);

    // Reset arrival counter every call (graph-capturable memset node).
    hipMemsetAsync(counter, 0, sizeof(int), stream);

    labelloss_fused_kernel<<<NBJ, TPB, 0, stream>>>(
        pred, gt, heatmap, wsv, wsi, counter, out);
}

// Round 5
// 31.694 us; speedup vs baseline: 1.4704x; 1.4704x over previous
//
#include <hip/hip_runtime.h>

#define Bq 32
#define Jq 16
#define Hq 256
#define Wq 256
#define Cn 7
#define HW (Hq * Wq)          // 65536 per (b,j)
#define NBJ (Bq * Jq)         // 512 blocks, one per (b,j)
#define TPB 256

__global__ __launch_bounds__(TPB) void labelloss_fused_kernel(
    const float* __restrict__ pred,
    const float* __restrict__ gt,
    const float* __restrict__ heatmap,
    float* __restrict__ out)
{
    const int bj  = blockIdx.x;        // 0..511
    const int b   = bj >> 4;
    const int tid = threadIdx.x;

    // ---- Phase 1: per-(b,j) argmax over 65536 floats (R0's best loop) ----
    const float4* hm = (const float4*)(heatmap + (size_t)bj * HW);

    float best = -3.402823466e+38f;
    int   bidx = 0x7fffffff;

    #pragma unroll 4
    for (int it = 0; it < HW / 4 / TPB; ++it) {
        const int v4   = it * TPB + tid;
        const float4 v = hm[v4];
        const int base = v4 * 4;
        // Strict '>' keeps earliest index (thread scans increasing idx).
        if (v.x > best) { best = v.x; bidx = base;     }
        if (v.y > best) { best = v.y; bidx = base + 1; }
        if (v.z > best) { best = v.z; bidx = base + 2; }
        if (v.w > best) { best = v.w; bidx = base + 3; }
    }

    // Wave-64 shuffle reduce; ties -> smaller flat index.
    #pragma unroll
    for (int off = 32; off > 0; off >>= 1) {
        const float ov = __shfl_down(best, off);
        const int   oi = __shfl_down(bidx, off);
        if (ov > best || (ov == best && oi < bidx)) { best = ov; bidx = oi; }
    }

    __shared__ float sval[TPB / 64];
    __shared__ int   sidx[TPB / 64];
    const int wave = tid >> 6;
    const int lane = tid & 63;
    if (lane == 0) { sval[wave] = best; sidx[wave] = bidx; }
    __syncthreads();

    // ---- Phase 2: block-local loss + one float atomicAdd. No fences. ----
    if (tid == 0) {
        #pragma unroll
        for (int w = 1; w < TPB / 64; ++w) {
            if (sval[w] > best || (sval[w] == best && sidx[w] < bidx)) {
                best = sval[w]; bidx = sidx[w];
            }
        }
        if (best == 1.0f) {
            const int x = bidx >> 8;       // idx / 256
            const int y = bidx & 255;      // idx % 256
            const float* gp = gt + (size_t)bj * Cn;
            float loss = 0.0f;
            #pragma unroll
            for (int c = 0; c < Cn; ++c) {   // 7 independent gathers in flight
                const float pv = pred[(((size_t)b * Cn + c) * Hq + x) * Wq + y];
                const float d  = pv - gp[c];
                loss += d * d;
            }
            atomicAdd(out + b, loss);      // device-coherent, no fence needed
        }
    }
}

extern "C" void kernel_launch(void* const* d_in, const int* in_sizes, int n_in,
                              void* d_out, int out_size, void* d_ws, size_t ws_size,
                              hipStream_t stream)
{
    const float* pred    = (const float*)d_in[0];   // (B, C, H, W) f32
    const float* gt      = (const float*)d_in[1];   // (B, J, C)   f32
    const float* heatmap = (const float*)d_in[2];   // (B, J, H, W) f32
    float* out = (float*)d_out;                     // (B,) f32

    // out must start at zero every call (atomics accumulate into it; the
    // harness does not re-poison between replays). 128-byte memset node.
    hipMemsetAsync(out, 0, Bq * sizeof(float), stream);

    labelloss_fused_kernel<<<NBJ, TPB, 0, stream>>>(pred, gt, heatmap, out);
}

// Round 7
// 26.941 us; speedup vs baseline: 1.7299x; 1.1764x over previous
//
#include <hip/hip_runtime.h>

#define Bq 32
#define Jq 16
#define Hq 256
#define Wq 256
#define Cn 7
#define HW (Hq * Wq)          // 65536 per (b,j)
#define NBJ (Bq * Jq)         // 512 blocks, one per (b,j)
#define TPB 256

typedef float f32x4 __attribute__((ext_vector_type(4)));

__global__ __launch_bounds__(TPB) void labelloss_argmax_kernel(
    const float* __restrict__ pred,
    const float* __restrict__ gt,
    const float* __restrict__ heatmap,
    float* __restrict__ ws)
{
    const int bj  = blockIdx.x;        // 0..511
    const int b   = bj >> 4;
    const int tid = threadIdx.x;

    // Stream this (b,j)'s 65536-float heatmap slice: 64 coalesced float4/thread.
    // Non-temporal: read-once data, skip cache write-allocate on the stream.
    const f32x4* hm = (const f32x4*)(heatmap + (size_t)bj * HW);

    float best = -3.402823466e+38f;
    int   bidx = 0x7fffffff;

    #pragma unroll 4
    for (int it = 0; it < HW / 4 / TPB; ++it) {
        const int v4   = it * TPB + tid;
        const f32x4 v  = __builtin_nontemporal_load(&hm[v4]);
        const int base = v4 * 4;
        // Strict '>' keeps the earliest index within this thread's
        // monotonically-increasing scan order (JAX argmax = first occurrence).
        if (v.x > best) { best = v.x; bidx = base;     }
        if (v.y > best) { best = v.y; bidx = base + 1; }
        if (v.z > best) { best = v.z; bidx = base + 2; }
        if (v.w > best) { best = v.w; bidx = base + 3; }
    }

    // Wave-64 shuffle reduce; ties -> smaller flat index.
    #pragma unroll
    for (int off = 32; off > 0; off >>= 1) {
        const float ov = __shfl_down(best, off);
        const int   oi = __shfl_down(bidx, off);
        if (ov > best || (ov == best && oi < bidx)) { best = ov; bidx = oi; }
    }

    __shared__ float sval[4];
    __shared__ int   sidx[4];
    const int wave = tid >> 6;
    const int lane = tid & 63;
    if (lane == 0) { sval[wave] = best; sidx[wave] = bidx; }
    __syncthreads();

    if (tid == 0) {
        #pragma unroll
        for (int w = 1; w < 4; ++w) {
            if (sval[w] > best || (sval[w] == best && sidx[w] < bidx)) {
                best = sval[w]; bidx = sidx[w];
            }
        }
        float loss = 0.0f;
        if (best == 1.0f) {
            const int x = bidx >> 8;    // idx / 256
            const int y = bidx & 255;   // idx % 256
            const float* gp = gt + (size_t)bj * Cn;
            #pragma unroll
            for (int c = 0; c < Cn; ++c) {
                const float pv = pred[(((size_t)b * Cn + c) * Hq + x) * Wq + y];
                const float d  = pv - gp[c];
                loss += d * d;
            }
        }
        ws[bj] = loss;   // written unconditionally -> no ws init needed
    }
}

__global__ void labelloss_sum_kernel(const float* __restrict__ ws,
                                     float* __restrict__ out)
{
    const int b = threadIdx.x;
    if (b < Bq) {
        float s = 0.0f;
        #pragma unroll
        for (int j = 0; j < Jq; ++j) s += ws[b * Jq + j];
        out[b] = s;      // all 32 outputs written unconditionally
    }
}

extern "C" void kernel_launch(void* const* d_in, const int* in_sizes, int n_in,
                              void* d_out, int out_size, void* d_ws, size_t ws_size,
                              hipStream_t stream)
{
    const float* pred    = (const float*)d_in[0];   // (B, C, H, W) f32
    const float* gt      = (const float*)d_in[1];   // (B, J, C)   f32
    const float* heatmap = (const float*)d_in[2];   // (B, J, H, W) f32
    float* out = (float*)d_out;                     // (B,) f32
    float* ws  = (float*)d_ws;                      // NBJ floats of scratch

    labelloss_argmax_kernel<<<NBJ, TPB, 0, stream>>>(pred, gt, heatmap, ws);
    labelloss_sum_kernel<<<1, 64, 0, stream>>>(ws, out);
}

// Round 8
// 25.225 us; speedup vs baseline: 1.8475x; 1.0680x over previous
//
#include <hip/hip_runtime.h>

#define Bq 32
#define Jq 16
#define Hq 256
#define Wq 256
#define Cn 7
#define HW (Hq * Wq)          // 65536 per (b,j)
#define NBJ (Bq * Jq)         // 512 blocks, one per (b,j)
#define TPB 256

typedef float f32x4 __attribute__((ext_vector_type(4)));

__global__ __launch_bounds__(TPB) void labelloss_argmax_kernel(
    const float* __restrict__ pred,
    const float* __restrict__ gt,
    const float* __restrict__ heatmap,
    float* __restrict__ ws)
{
    const int bj  = blockIdx.x;        // 0..511
    const int b   = bj >> 4;
    const int tid = threadIdx.x;

    // Stream this (b,j)'s 65536-float heatmap slice: 64 coalesced float4/thread.
    // Non-temporal (read-once): skip cache allocate. unroll 8 -> 8 NT loads
    // in flight per wave to cover full-HBM latency (no L2 assist on NT path).
    const f32x4* hm = (const f32x4*)(heatmap + (size_t)bj * HW);

    float best = -3.402823466e+38f;
    int   bidx = 0x7fffffff;

    #pragma unroll 8
    for (int it = 0; it < HW / 4 / TPB; ++it) {
        const int v4   = it * TPB + tid;
        const f32x4 v  = __builtin_nontemporal_load(&hm[v4]);
        const int base = v4 * 4;
        // Strict '>' keeps the earliest index within this thread's
        // monotonically-increasing scan order (JAX argmax = first occurrence).
        if (v.x > best) { best = v.x; bidx = base;     }
        if (v.y > best) { best = v.y; bidx = base + 1; }
        if (v.z > best) { best = v.z; bidx = base + 2; }
        if (v.w > best) { best = v.w; bidx = base + 3; }
    }

    // Wave-64 shuffle reduce; ties -> smaller flat index.
    #pragma unroll
    for (int off = 32; off > 0; off >>= 1) {
        const float ov = __shfl_down(best, off);
        const int   oi = __shfl_down(bidx, off);
        if (ov > best || (ov == best && oi < bidx)) { best = ov; bidx = oi; }
    }

    __shared__ float sval[4];
    __shared__ int   sidx[4];
    const int wave = tid >> 6;
    const int lane = tid & 63;
    if (lane == 0) { sval[wave] = best; sidx[wave] = bidx; }
    __syncthreads();

    if (tid == 0) {
        #pragma unroll
        for (int w = 1; w < 4; ++w) {
            if (sval[w] > best || (sval[w] == best && sidx[w] < bidx)) {
                best = sval[w]; bidx = sidx[w];
            }
        }
        float loss = 0.0f;
        if (best == 1.0f) {
            const int x = bidx >> 8;    // idx / 256
            const int y = bidx & 255;   // idx % 256
            const float* gp = gt + (size_t)bj * Cn;
            #pragma unroll
            for (int c = 0; c < Cn; ++c) {
                const float pv = pred[(((size_t)b * Cn + c) * Hq + x) * Wq + y];
                const float d  = pv - gp[c];
                loss += d * d;
            }
        }
        ws[bj] = loss;   // written unconditionally -> no ws init needed
    }
}

__global__ void labelloss_sum_kernel(const float* __restrict__ ws,
                                     float* __restrict__ out)
{
    const int b = threadIdx.x;
    if (b < Bq) {
        float s = 0.0f;
        #pragma unroll
        for (int j = 0; j < Jq; ++j) s += ws[b * Jq + j];
        out[b] = s;      // all 32 outputs written unconditionally
    }
}

extern "C" void kernel_launch(void* const* d_in, const int* in_sizes, int n_in,
                              void* d_out, int out_size, void* d_ws, size_t ws_size,
                              hipStream_t stream)
{
    const float* pred    = (const float*)d_in[0];   // (B, C, H, W) f32
    const float* gt      = (const float*)d_in[1];   // (B, J, C)   f32
    const float* heatmap = (const float*)d_in[2];   // (B, J, H, W) f32
    float* out = (float*)d_out;                     // (B,) f32
    float* ws  = (float*)d_ws;                      // NBJ floats of scratch

    labelloss_argmax_kernel<<<NBJ, TPB, 0, stream>>>(pred, gt, heatmap, ws);
    labelloss_sum_kernel<<<1, 64, 0, stream>>>(ws, out);
}